// Round 1
// baseline (72.963 us; speedup 1.0000x reference)
//
#include <hip/hip_runtime.h>
#include <hip/hip_bf16.h>

// Problem: P=2048 patches, D=256 features.
// loss = mean_{p,i,j} | q[p,i]*q[p,j] - k[p,i]*k[p,j] |
//
// Kernel 1: one block per patch. Stage q-row/k-row in LDS (1 KB each).
//           Thread i accumulates over j (wave-uniform LDS broadcast reads).
//           Block partial -> d_ws[blockIdx] (each block owns its slot; no
//           dependence on d_ws initial contents, which are poisoned 0xAA).
// Kernel 2: single block reduces 2048 partials, writes mean to d_out[0].

#define PATCHES 2048
#define DIM 256

__global__ __launch_bounds__(DIM) void patch_l1_partial(
    const float* __restrict__ q,
    const float* __restrict__ k,
    float* __restrict__ partial)
{
    __shared__ float qs[DIM];
    __shared__ float ks[DIM];

    const int p = blockIdx.x;
    const int t = threadIdx.x;          // 0..255

    const float* __restrict__ qrow = q + (size_t)p * DIM;
    const float* __restrict__ krow = k + (size_t)p * DIM;

    const float qi = qrow[t];
    const float ki = krow[t];
    qs[t] = qi;
    ks[t] = ki;
    __syncthreads();

    float acc = 0.0f;
#pragma unroll 8
    for (int j = 0; j < DIM; ++j) {
        // q_i*q_j - k_i*k_j : mul + fma; abs folds into the add's src modifier
        const float v = qi * qs[j] - ki * ks[j];
        acc += fabsf(v);
    }

    // wave (64-lane) shuffle reduction
#pragma unroll
    for (int off = 32; off > 0; off >>= 1)
        acc += __shfl_down(acc, off, 64);

    __shared__ float wsum[4];
    const int wave = t >> 6;
    const int lane = t & 63;
    if (lane == 0) wsum[wave] = acc;
    __syncthreads();

    if (t == 0)
        partial[p] = (wsum[0] + wsum[1]) + (wsum[2] + wsum[3]);
}

__global__ __launch_bounds__(256) void patch_l1_final(
    const float* __restrict__ partial,
    float* __restrict__ out)
{
    const int t = threadIdx.x;
    float acc = 0.0f;
#pragma unroll
    for (int i = t; i < PATCHES; i += 256)
        acc += partial[i];

#pragma unroll
    for (int off = 32; off > 0; off >>= 1)
        acc += __shfl_down(acc, off, 64);

    __shared__ float wsum[4];
    if ((t & 63) == 0) wsum[t >> 6] = acc;
    __syncthreads();

    if (t == 0) {
        const float s = (wsum[0] + wsum[1]) + (wsum[2] + wsum[3]);
        const double denom = (double)PATCHES * (double)DIM * (double)DIM;
        out[0] = (float)((double)s / denom);
    }
}

extern "C" void kernel_launch(void* const* d_in, const int* in_sizes, int n_in,
                              void* d_out, int out_size, void* d_ws, size_t ws_size,
                              hipStream_t stream)
{
    const float* q = (const float*)d_in[0];
    const float* k = (const float*)d_in[1];
    float* out = (float*)d_out;
    float* partial = (float*)d_ws;      // 2048 floats = 8 KB

    patch_l1_partial<<<PATCHES, DIM, 0, stream>>>(q, k, partial);
    patch_l1_final<<<1, 256, 0, stream>>>(partial, out);
}

// Round 2
// 70.421 us; speedup vs baseline: 1.0361x; 1.0361x over previous
//
#include <hip/hip_runtime.h>
#include <hip/hip_bf16.h>

// P=2048 patches, D=256. loss = mean_{p,i,j} |q[p,i]q[p,j] - k[p,i]k[p,j]|
//
// R2 design: one wave per patch. Row staged in LDS as float4.
//   lane 0-31 : 8 columns each (all 256 cols), j in [0,128)
//   lane 32-63: same columns, j in [128,256)
// Per wave: 64 ds_read_b128 (wave has only 2 distinct addrs per read ->
// broadcast, conflict-free) vs 3072 VALU insts -> VALU-issue-bound.
// Block = 256 threads = 4 waves = 4 patches; grid = 512 blocks.

#define PATCHES 2048
#define DIM 256
#define PPB 4   // patches per block (one per wave)

__global__ __launch_bounds__(256) void patch_l1_partial(
    const float4* __restrict__ q4,
    const float4* __restrict__ k4,
    float* __restrict__ partial)
{
    __shared__ float4 qs[PPB][DIM / 4];   // 4 KB
    __shared__ float4 ks[PPB][DIM / 4];   // 4 KB

    const int t  = threadIdx.x;
    const int p0 = blockIdx.x * PPB;

    // Stage 4 patches (q & k): 256 threads x 1 float4 per array, coalesced.
    {
        const int lp = t >> 6;    // local patch 0..3
        const int e  = t & 63;    // float4 index within row
        qs[lp][e] = q4[(size_t)(p0 + lp) * (DIM / 4) + e];
        ks[lp][e] = k4[(size_t)(p0 + lp) * (DIM / 4) + e];
    }
    __syncthreads();

    const int wave = t >> 6;      // local patch
    const int lane = t & 63;
    const int half = lane >> 5;   // j-half selector
    const int cg   = lane & 31;   // column group: owns cols 8*cg..8*cg+7

    const float4 qi0 = qs[wave][2 * cg];
    const float4 qi1 = qs[wave][2 * cg + 1];
    const float4 ki0 = ks[wave][2 * cg];
    const float4 ki1 = ks[wave][2 * cg + 1];

    const int jb0 = half * 32;    // 32 float4 steps = 128 j values

    float a0 = 0.f, a1 = 0.f, a2 = 0.f, a3 = 0.f;

#define ACC4(A, QV, KV, C)                              \
    A += fabsf(QV.C * qj.x - KV.C * kj.x);              \
    A += fabsf(QV.C * qj.y - KV.C * kj.y);              \
    A += fabsf(QV.C * qj.z - KV.C * kj.z);              \
    A += fabsf(QV.C * qj.w - KV.C * kj.w);

#pragma unroll 4
    for (int jb = 0; jb < 32; ++jb) {
        const float4 qj = qs[wave][jb0 + jb];
        const float4 kj = ks[wave][jb0 + jb];
        ACC4(a0, qi0, ki0, x)
        ACC4(a1, qi0, ki0, y)
        ACC4(a2, qi0, ki0, z)
        ACC4(a3, qi0, ki0, w)
        ACC4(a0, qi1, ki1, x)
        ACC4(a1, qi1, ki1, y)
        ACC4(a2, qi1, ki1, z)
        ACC4(a3, qi1, ki1, w)
    }
#undef ACC4

    float acc = (a0 + a1) + (a2 + a3);

    // 64-lane reduction -> one partial per patch
#pragma unroll
    for (int off = 32; off > 0; off >>= 1)
        acc += __shfl_down(acc, off, 64);

    if (lane == 0)
        partial[p0 + wave] = acc;
}

__global__ __launch_bounds__(256) void patch_l1_final(
    const float* __restrict__ partial,
    float* __restrict__ out)
{
    const int t = threadIdx.x;
    float acc = 0.0f;
#pragma unroll
    for (int i = t; i < PATCHES; i += 256)
        acc += partial[i];

#pragma unroll
    for (int off = 32; off > 0; off >>= 1)
        acc += __shfl_down(acc, off, 64);

    __shared__ float wsum[4];
    if ((t & 63) == 0) wsum[t >> 6] = acc;
    __syncthreads();

    if (t == 0) {
        const float s = (wsum[0] + wsum[1]) + (wsum[2] + wsum[3]);
        const double denom = (double)PATCHES * (double)DIM * (double)DIM;
        out[0] = (float)((double)s / denom);
    }
}

extern "C" void kernel_launch(void* const* d_in, const int* in_sizes, int n_in,
                              void* d_out, int out_size, void* d_ws, size_t ws_size,
                              hipStream_t stream)
{
    const float4* q4 = (const float4*)d_in[0];
    const float4* k4 = (const float4*)d_in[1];
    float* out = (float*)d_out;
    float* partial = (float*)d_ws;   // 2048 floats = 8 KB

    patch_l1_partial<<<PATCHES / PPB, 256, 0, stream>>>(q4, k4, partial);
    patch_l1_final<<<1, 256, 0, stream>>>(partial, out);
}